// Round 8
// baseline (102.032 us; speedup 1.0000x reference)
//
#include <hip/hip_runtime.h>
#include <hip/hip_bf16.h>

#define D_ 256
#define HW_ 1024

typedef short short4v __attribute__((ext_vector_type(4)));
typedef short short8 __attribute__((ext_vector_type(8)));
typedef float float4v __attribute__((ext_vector_type(4)));

__device__ __forceinline__ unsigned short f2bf(float f) {
  unsigned u = __builtin_bit_cast(unsigned, f);
  return (unsigned short)((u + 0x7fffu + ((u >> 16) & 1u)) >> 16);
}
__device__ __forceinline__ float bf2f(unsigned short h) {
  return __builtin_bit_cast(float, ((unsigned)h) << 16);
}

// ---- prep: cnorm + bf16(-2c) in MFMA A-fragment order ----
// frag(g=code>>4, kk)[lane=q*16+c] = code g*16+c, feats kk*32+q*8..+7
__global__ __launch_bounds__(256) void vq_prep(const float* __restrict__ cb,
                                               unsigned short* __restrict__ cbfrag,
                                               float* __restrict__ cnorm) {
  int k = blockIdx.x;   // code 0..1023
  int t = threadIdx.x;  // feature 0..255
  float c = cb[k * D_ + t];
  float s = c * c;
#pragma unroll
  for (int off = 1; off < 64; off <<= 1) s += __shfl_xor(s, off, 64);
  __shared__ float wsum[4];
  if ((t & 63) == 0) wsum[t >> 6] = s;
  __syncthreads();
  if (t == 0) cnorm[k] = wsum[0] + wsum[1] + wsum[2] + wsum[3];
  int g = k >> 4, cc = k & 15;
  int kk = t >> 5, q = (t >> 3) & 3, e = t & 7;
  cbfrag[(((g * 8) + kk) * 64 + q * 16 + cc) * 8 + e] = f2bf(-2.0f * c);
}

// ---- main: barrier-free distance loop, codebook register-resident ----
// 512 blocks x 256 thr (4 waves), 128 pts/block in LDS (read-only during loop).
// Wave w covers codes [w*256,(w+1)*256) via 4 register-resident quarters.
__global__ __launch_bounds__(256) void vq_main(const float* __restrict__ lat,
                                               const short8* __restrict__ cbfrag,
                                               const float* __restrict__ cnorm,
                                               const float* __restrict__ cb,
                                               float* __restrict__ out,
                                               float* __restrict__ part) {
  __shared__ unsigned short img[32768];  // 128 rows(points) x 512B, swizzled (64KB)
  __shared__ float fnp[4][128];
  __shared__ float fnl[128];
  __shared__ float mD[4][128];
  __shared__ int mI[4][128];
  __shared__ int idx_s[128];

  const int tid = threadIdx.x;
  const int w = tid >> 6, lane = tid & 63;
  const int q = lane >> 4, c = lane & 15;
  const int blk = blockIdx.x;
  const int b = blk >> 3, hwb = (blk & 7) << 7;

  // ---- stage 128 pts: coalesced dword loads -> f2bf -> b128 swizzled writes;
  //      fp32 |f|^2 partials on the side ----
#pragma unroll 1
  for (int tile = 0; tile < 2; ++tile) {
    float a = 0.f;
#pragma unroll 4
    for (int jj = 0; jj < 8; ++jj) {
      int j = w * 8 + jj;  // feature octet
      short8 v;
#pragma unroll
      for (int e = 0; e < 8; ++e) {
        float f = lat[((size_t)(b * D_ + j * 8 + e)) * HW_ + hwb + tile * 64 + lane];
        a += f * f;
        v[e] = (short)f2bf(f);
      }
      int row = tile * 64 + lane;
      *(short8*)&img[row * 256 + ((j * 8) ^ ((row & 15) << 4))] = v;
    }
    fnp[w][tile * 64 + lane] = a;
  }
  __syncthreads();
  if (tid < 128) fnl[tid] = fnp[0][tid] + fnp[1][tid] + fnp[2][tid] + fnp[3][tid];

  // ---- main loop: 4 code-quarters, NO barriers ----
  float runD[8];
  int runI[8];
#pragma unroll
  for (int pf = 0; pf < 8; ++pf) { runD[pf] = 3.0e38f; runI[pf] = 0x7fffffff; }

#pragma unroll 1
  for (int cq = 0; cq < 4; ++cq) {
    short8 afr[4][8];  // 64 codes resident: 128 VGPR
#pragma unroll
    for (int a = 0; a < 4; ++a)
#pragma unroll
      for (int kk = 0; kk < 8; ++kk)
        afr[a][kk] = cbfrag[((w * 16 + cq * 4 + a) * 8 + kk) * 64 + lane];
    float4v cn[4];
#pragma unroll
    for (int a = 0; a < 4; ++a)
      cn[a] = *(const float4v*)&cnorm[w * 256 + cq * 64 + a * 16 + q * 4];
#pragma unroll
    for (int pf = 0; pf < 8; ++pf) {
      float4v acc[4];
#pragma unroll
      for (int a = 0; a < 4; ++a) acc[a] = cn[a];
      const int row = pf * 16 + c;
#pragma unroll
      for (int kk = 0; kk < 8; ++kk) {
        short8 bf = *(const short8*)
            &img[row * 256 + ((((kk << 2) | q) * 8) ^ ((row & 15) << 4))];
#pragma unroll
        for (int a = 0; a < 4; ++a)
          acc[a] = __builtin_amdgcn_mfma_f32_16x16x32_bf16(afr[a][kk], bf, acc[a],
                                                           0, 0, 0);
      }
      // lane-local scan (codes ascend with cq,a,r => strict < = first occurrence)
#pragma unroll
      for (int a = 0; a < 4; ++a) {
        int cb0 = w * 256 + cq * 64 + a * 16 + q * 4;
#pragma unroll
        for (int r = 0; r < 4; ++r) {
          float dv = acc[a][r];
          if (dv < runD[pf]) { runD[pf] = dv; runI[pf] = cb0 + r; }
        }
      }
    }
  }

  // ---- deferred butterfly (q-rows) then 4-way cross-wave merge ----
#pragma unroll
  for (int pf = 0; pf < 8; ++pf) {
#pragma unroll
    for (int di = 16; di < 64; di <<= 1) {
      float od = __shfl_xor(runD[pf], di, 64);
      int oi = __shfl_xor(runI[pf], di, 64);
      if (od < runD[pf] || (od == runD[pf] && oi < runI[pf])) {
        runD[pf] = od; runI[pf] = oi;
      }
    }
    if (lane < 16) { mD[w][pf * 16 + lane] = runD[pf]; mI[w][pf * 16 + lane] = runI[pf]; }
  }
  __syncthreads();
  if (tid < 128) {
    float dB = mD[0][tid];
    int iB = mI[0][tid];
#pragma unroll
    for (int w2 = 1; w2 < 4; ++w2) {  // quarters ascend in code idx: strict <
      float d2 = mD[w2][tid];
      if (d2 < dB) { dB = d2; iB = mI[w2][tid]; }
    }
    idx_s[tid] = iB;
    fnl[tid] = dB + fnl[tid];  // ||f - c_best||^2
  }
  __syncthreads();
  if (tid < 64) {
    float s = fnl[tid] + fnl[tid + 64];
#pragma unroll
    for (int off = 1; off < 64; off <<= 1) s += __shfl_xor(s, off, 64);
    if (tid == 0) part[blk] = s;
  }

  // ---- cooperative gather: whole cb rows (1KB float4/instr) -> bf16 img ----
#pragma unroll 4
  for (int rp = 0; rp < 32; ++rp) {
    int row = rp * 4 + w;
    int gidx = idx_s[row];
    float4v cv = ((const float4v*)(cb + (size_t)gidx * D_))[lane];
    short4v sv;
#pragma unroll
    for (int i = 0; i < 4; ++i) sv[i] = (short)f2bf(cv[i]);
    *(short4v*)&img[row * 256 + ((lane * 4) ^ ((row & 15) << 4))] = sv;
  }
  __syncthreads();
  // ---- coalesced [B,D,H,W] stores ----
#pragma unroll 1
  for (int st = 0; st < 2; ++st) {
#pragma unroll
    for (int jo = 0; jo < 8; ++jo) {
      int j = w * 8 + jo;
      int row = st * 64 + lane;
      short8 v = *(const short8*)&img[row * 256 + ((j * 8) ^ ((row & 15) << 4))];
#pragma unroll
      for (int e = 0; e < 8; ++e)
        out[((size_t)(b * D_ + j * 8 + e)) * HW_ + hwb + st * 64 + lane] =
            bf2f((unsigned short)v[e]);
    }
  }
}

// ---- finalize: loss = 1.25 * mean (512 partials) ----
__global__ __launch_bounds__(256) void vq_fin(const float* __restrict__ part,
                                              float* __restrict__ outs) {
  int t = threadIdx.x;
  float s = part[t] + part[t + 256];
#pragma unroll
  for (int off = 1; off < 64; off <<= 1) s += __shfl_xor(s, off, 64);
  __shared__ float w4[4];
  if ((t & 63) == 0) w4[t >> 6] = s;
  __syncthreads();
  if (t == 0) *outs = (w4[0] + w4[1] + w4[2] + w4[3]) * (1.25f / 16777216.0f);
}

extern "C" void kernel_launch(void* const* d_in, const int* in_sizes, int n_in,
                              void* d_out, int out_size, void* d_ws, size_t ws_size,
                              hipStream_t stream) {
  const float* lat = (const float*)d_in[0];
  const float* cb = (const float*)d_in[1];
  float* out = (float*)d_out;
  char* ws = (char*)d_ws;
  unsigned short* cbfrag = (unsigned short*)ws;  // 512 KB (bf16 -2c frag image)
  float* cnorm = (float*)(ws + 524288);          // 4 KB
  float* partial = (float*)(ws + 528384);        // 2 KB (512 floats)

  vq_prep<<<1024, 256, 0, stream>>>(cb, cbfrag, cnorm);
  vq_main<<<512, 256, 0, stream>>>(lat, (const short8*)cbfrag, cnorm, cb, out,
                                   partial);
  vq_fin<<<1, 256, 0, stream>>>(partial, out + 16777216);
}

// Round 9
// 63.889 us; speedup vs baseline: 1.5970x; 1.5970x over previous
//
#include <hip/hip_runtime.h>
#include <hip/hip_bf16.h>

#define D_ 256
#define HW_ 1024

typedef short short4v __attribute__((ext_vector_type(4)));
typedef short short8 __attribute__((ext_vector_type(8)));
typedef float float4v __attribute__((ext_vector_type(4)));

__device__ __forceinline__ unsigned short f2bf(float f) {
  unsigned u = __builtin_bit_cast(unsigned, f);
  return (unsigned short)((u + 0x7fffu + ((u >> 16) & 1u)) >> 16);
}
__device__ __forceinline__ float bf2f(unsigned short h) {
  return __builtin_bit_cast(float, ((unsigned)h) << 16);
}

__device__ __forceinline__ void async16(void* lds, const void* g) {
  __builtin_amdgcn_global_load_lds(
      (__attribute__((address_space(1))) const unsigned int*)g,
      (__attribute__((address_space(3))) unsigned int*)lds, 16, 0, 0);
}

// ---- prep: cnorm + bf16(-2c) in MFMA A-fragment order ----
// cbfrag[((g*8)+kk)*64 + q*16 + cc] (short8) = code g*16+cc, feats kk*32+q*8..+7
__global__ __launch_bounds__(256) void vq_prep(const float* __restrict__ cb,
                                               unsigned short* __restrict__ cbfrag,
                                               float* __restrict__ cnorm) {
  int k = blockIdx.x;   // code 0..1023
  int t = threadIdx.x;  // feature 0..255
  float c = cb[k * D_ + t];
  float s = c * c;
#pragma unroll
  for (int off = 1; off < 64; off <<= 1) s += __shfl_xor(s, off, 64);
  __shared__ float wsum[4];
  if ((t & 63) == 0) wsum[t >> 6] = s;
  __syncthreads();
  if (t == 0) cnorm[k] = wsum[0] + wsum[1] + wsum[2] + wsum[3];
  int g = k >> 4, cc = k & 15;
  int kk = t >> 5, q = (t >> 3) & 3, e = t & 7;
  cbfrag[(((g * 8) + kk) * 64 + q * 16 + cc) * 8 + e] = f2bf(-2.0f * c);
}

// ---- main: counted-vmcnt pipelined distance loop (T3+T4+T5) ----
// 512 blocks x 256 thr (4 waves = 2 pg x 2 ch), 128 pts/block.
// 32-code chunks in 4 x 16KB LDS slots, prefetch 3 ahead, vmcnt(8) steady-state.
__global__ __launch_bounds__(256) void vq_main(const float* __restrict__ lat,
                                               const short8* __restrict__ cbfrag,
                                               const float* __restrict__ cnorm,
                                               int* __restrict__ idx_out,
                                               float* __restrict__ part) {
  __shared__ short8 slots[4][1024];   // 64KB: point tiles first, then cb slots
  __shared__ float cnorm_s[1024];     // 4KB (keeps global loads out of the loop)
  __shared__ float mergeD[128];
  __shared__ int mergeI[128];

  const int tid = threadIdx.x;
  const int w = tid >> 6, lane = tid & 63;
  const int pg = w >> 1, ch = w & 1;
  const int q = lane >> 4, c = lane & 15;
  const int blk = blockIdx.x;
  const int b = blk >> 3, hwb = (blk & 7) << 7;

  cnorm_s[tid] = cnorm[tid];
  cnorm_s[tid + 256] = cnorm[tid + 256];
  cnorm_s[tid + 512] = cnorm[tid + 512];
  cnorm_s[tid + 768] = cnorm[tid + 768];

  // ---- stage 128 pts (proven R7 pattern: coalesced loads, b128 swizzled) ----
  unsigned short* img = (unsigned short*)&slots[0][0];  // 128 rows x 512B
#pragma unroll 1
  for (int t = 0; t < 2; ++t) {
#pragma unroll 4
    for (int jj = 0; jj < 8; ++jj) {
      int j = w * 8 + jj;
      short8 v;
#pragma unroll
      for (int e = 0; e < 8; ++e) {
        float f = lat[((size_t)(b * D_ + j * 8 + e)) * HW_ + hwb + t * 64 + lane];
        v[e] = (short)f2bf(f);
      }
      int row = t * 64 + lane;
      *(short8*)&img[row * 256 + ((j * 8) ^ ((row & 15) << 4))] = v;
    }
  }
  __syncthreads();

  // ---- extract B-frags + |f|^2 (waves 2pg,2pg+1 read rows pg*64..) ----
  short8 bfrag[4][8];
  float fn[4];
#pragma unroll
  for (int pf = 0; pf < 4; ++pf) {
    int row = pg * 64 + pf * 16 + c;
#pragma unroll
    for (int kk = 0; kk < 8; ++kk) {
      int s = (kk << 2) | q;
      bfrag[pf][kk] =
          *(const short8*)&img[row * 256 + ((s * 8) ^ ((row & 15) << 4))];
    }
    float a = 0.f;
#pragma unroll
    for (int kk = 0; kk < 8; ++kk)
#pragma unroll
      for (int e = 0; e < 8; ++e) {
        float f = bf2f((unsigned short)bfrag[pf][kk][e]);
        a += f * f;
      }
    fn[pf] = a;
  }
#pragma unroll
  for (int pf = 0; pf < 4; ++pf) {
    fn[pf] += __shfl_xor(fn[pf], 16, 64);
    fn[pf] += __shfl_xor(fn[pf], 32, 64);
  }
  __syncthreads();  // tiles consumed (drains lgkm); slots free for codebook

  // ---- prologue: issue chunks 0,1,2 into slots 0,1,2 (12 outstanding) ----
#pragma unroll
  for (int ck = 0; ck < 3; ++ck)
#pragma unroll
    for (int r = 0; r < 4; ++r)
      async16(&slots[ck][r * 256 + tid], cbfrag + (ck * 1024 + r * 256 + tid));

  float runD[4];
  int runI[4];
#pragma unroll
  for (int pf = 0; pf < 4; ++pf) { runD[pf] = 3.0e38f; runI[pf] = 0x7fffffff; }

  // ---- 32 chunks; per iter: counted wait -> barrier -> MFMA -> issue i+3 ----
#pragma unroll 1
  for (int i = 0; i < 32; ++i) {
    if (i < 30) asm volatile("s_waitcnt vmcnt(8)" ::: "memory");
    else if (i == 30) asm volatile("s_waitcnt vmcnt(4)" ::: "memory");
    else asm volatile("s_waitcnt vmcnt(0)" ::: "memory");
    __builtin_amdgcn_s_barrier();
    __builtin_amdgcn_sched_barrier(0);

    float4v cn = *(const float4v*)&cnorm_s[i * 32 + ch * 16 + q * 4];
    float4v acc[4];
#pragma unroll
    for (int pf = 0; pf < 4; ++pf) acc[pf] = cn;
    const short8* slot = &slots[i & 3][0];
    __builtin_amdgcn_s_setprio(1);
#pragma unroll
    for (int kk = 0; kk < 8; ++kk) {
      short8 afr = slot[(ch * 8 + kk) * 64 + lane];
#pragma unroll
      for (int pf = 0; pf < 4; ++pf)
        acc[pf] = __builtin_amdgcn_mfma_f32_16x16x32_bf16(afr, bfrag[pf][kk],
                                                          acc[pf], 0, 0, 0);
    }
    __builtin_amdgcn_s_setprio(0);
    __builtin_amdgcn_sched_barrier(0);

    // lane-local scan (ascending code index; strict < = first occurrence)
#pragma unroll
    for (int pf = 0; pf < 4; ++pf) {
      int cb0 = i * 32 + ch * 16 + q * 4;
#pragma unroll
      for (int r = 0; r < 4; ++r) {
        float dv = acc[pf][r];
        if (dv < runD[pf]) { runD[pf] = dv; runI[pf] = cb0 + r; }
      }
    }
    if (i < 29) {
      int ck = i + 3;
      short8* dst = &slots[ck & 3][0];
      const short8* src = cbfrag + ck * 1024;
#pragma unroll
      for (int r = 0; r < 4; ++r) async16(&dst[r * 256 + tid], src + r * 256 + tid);
    }
  }

  // ---- deferred butterfly + cross-wave (ch) merge; idx + loss ----
#pragma unroll
  for (int pf = 0; pf < 4; ++pf) {
#pragma unroll
    for (int di = 16; di < 64; di <<= 1) {
      float od = __shfl_xor(runD[pf], di, 64);
      int oi = __shfl_xor(runI[pf], di, 64);
      if (od < runD[pf] || (od == runD[pf] && oi < runI[pf])) {
        runD[pf] = od; runI[pf] = oi;
      }
    }
  }
  float selD = q == 0 ? runD[0] : q == 1 ? runD[1] : q == 2 ? runD[2] : runD[3];
  int selI = q == 0 ? runI[0] : q == 1 ? runI[1] : q == 2 ? runI[2] : runI[3];
  float selF = q == 0 ? fn[0] : q == 1 ? fn[1] : q == 2 ? fn[2] : fn[3];
  int p = pg * 64 + q * 16 + c;
  if (ch == 1) { mergeD[p] = selD; mergeI[p] = selI; }
  __syncthreads();
  if (ch == 0) {
    float od = mergeD[p];
    int oi = mergeI[p];
    if (od < selD || (od == selD && oi < selI)) { selD = od; selI = oi; }
    idx_out[blk * 128 + p] = selI;
    float lv = selD + selF;  // ||f - c_best||^2
#pragma unroll
    for (int off = 1; off < 64; off <<= 1) lv += __shfl_xor(lv, off, 64);
    if (lane == 0) part[blk * 2 + pg] = lv;
  }
}

// ---- gather: out[b,d,hw] = cb[idx[hw]][d]; 1024 blocks, 4 blocks/CU ----
__global__ __launch_bounds__(256) void vq_gather(const float* __restrict__ cb,
                                                 const int* __restrict__ idx,
                                                 float* __restrict__ out) {
  __shared__ unsigned short gimg[16384];  // 64 rows x 512B, swizzled (32KB)
  __shared__ int sidx[64];
  const int tid = threadIdx.x;
  const int w = tid >> 6, lane = tid & 63;
  const int pt0 = blockIdx.x * 64;
  const int b = pt0 >> 10, hw0 = pt0 & 1023;
  if (tid < 64) sidx[tid] = idx[pt0 + tid];
  __syncthreads();
  // cooperative: wave reads whole cb rows (1KB float4/instr), bf16 to LDS
#pragma unroll 4
  for (int rp = 0; rp < 16; ++rp) {
    int row = rp * 4 + w;
    int gidx = sidx[row];
    float4v cv = ((const float4v*)(cb + (size_t)gidx * D_))[lane];
    short4v sv;
#pragma unroll
    for (int i = 0; i < 4; ++i) sv[i] = (short)f2bf(cv[i]);
    *(short4v*)&gimg[row * 256 + ((lane * 4) ^ ((row & 15) << 4))] = sv;
  }
  __syncthreads();
  // coalesced [B,D,H,W] stores (fp32 values round-trip bf16: << threshold)
#pragma unroll
  for (int jo = 0; jo < 8; ++jo) {
    int j = w * 8 + jo;
    short8 v = *(const short8*)&gimg[lane * 256 + ((j * 8) ^ ((lane & 15) << 4))];
#pragma unroll
    for (int e = 0; e < 8; ++e)
      out[((size_t)(b * D_ + j * 8 + e)) * HW_ + hw0 + lane] =
          bf2f((unsigned short)v[e]);
  }
}

// ---- finalize: loss = 1.25 * mean (1024 partials) ----
__global__ __launch_bounds__(256) void vq_fin(const float* __restrict__ part,
                                              float* __restrict__ outs) {
  int t = threadIdx.x;
  float s = part[t] + part[t + 256] + part[t + 512] + part[t + 768];
#pragma unroll
  for (int off = 1; off < 64; off <<= 1) s += __shfl_xor(s, off, 64);
  __shared__ float w4[4];
  if ((t & 63) == 0) w4[t >> 6] = s;
  __syncthreads();
  if (t == 0) *outs = (w4[0] + w4[1] + w4[2] + w4[3]) * (1.25f / 16777216.0f);
}

extern "C" void kernel_launch(void* const* d_in, const int* in_sizes, int n_in,
                              void* d_out, int out_size, void* d_ws, size_t ws_size,
                              hipStream_t stream) {
  const float* lat = (const float*)d_in[0];
  const float* cb = (const float*)d_in[1];
  float* out = (float*)d_out;
  char* ws = (char*)d_ws;
  unsigned short* cbfrag = (unsigned short*)ws;  // 512 KB (bf16 -2c frag image)
  float* cnorm = (float*)(ws + 524288);          // 4 KB
  int* idxbuf = (int*)(ws + 528384);             // 256 KB
  float* partial = (float*)(ws + 790528);        // 4 KB (1024 floats)

  vq_prep<<<1024, 256, 0, stream>>>(cb, cbfrag, cnorm);
  vq_main<<<512, 256, 0, stream>>>(lat, (const short8*)cbfrag, cnorm, idxbuf,
                                   partial);
  vq_gather<<<1024, 256, 0, stream>>>(cb, idxbuf, out);
  vq_fin<<<1, 256, 0, stream>>>(partial, out + 16777216);
}